// Round 1
// baseline (1190.528 us; speedup 1.0000x reference)
//
#include <hip/hip_runtime.h>
#include <math.h>

#define NN 50000
#define EE 800000
// DIN = DOUT = 128, DEDGE = 64, HEADS = 1

// ---------------------------------------------------------------------------
// K0: weight prep  WQE[r][m] = sum_c Wq[r][c] * We[m][c]   (Wq @ We^T, [128,64])
//     BQE[m]       = sum_c bq[c] * We[m][c]
// ---------------------------------------------------------------------------
__global__ __launch_bounds__(256) void k_wprep(const float* __restrict__ Wq,
                                               const float* __restrict__ bq,
                                               const float* __restrict__ We,
                                               float* __restrict__ wqe,
                                               float* __restrict__ bqe)
{
    int idx = blockIdx.x * 256 + threadIdx.x;
    if (idx < 8192) {
        int r = idx >> 6, m = idx & 63;
        float acc = 0.f;
        for (int c = 0; c < 128; ++c) acc += Wq[r * 128 + c] * We[m * 128 + c];
        wqe[r * 64 + m] = acc;
    } else if (idx < 8256) {
        int m = idx - 8192;
        float acc = 0.f;
        for (int c = 0; c < 128; ++c) acc += bq[c] * We[m * 128 + c];
        bqe[m] = acc;
    }
}

// ---------------------------------------------------------------------------
// K1: fused node projections. Conceptual col space (768 padded, 705 active):
//   [0,128) Q | [128,256) K | [256,384) V | [384,512) SKIP |
//   [512,640) RES | [640,704) WEQ (stride 64) | 704 GATE (sigmoid)
// 32 nodes per block; weight column cached in 64 VGPRs per K-half;
// x row accessed via block-uniform address (compiler emits s_load).
// ---------------------------------------------------------------------------
#define ROWS 32
__global__ __launch_bounds__(256) void k_nodeproj(
    const float* __restrict__ x,
    const float* __restrict__ Wq, const float* __restrict__ bq,
    const float* __restrict__ Wk, const float* __restrict__ bk,
    const float* __restrict__ Wv, const float* __restrict__ bv,
    const float* __restrict__ Wskip, const float* __restrict__ bskip,
    const float* __restrict__ Wres, const float* __restrict__ bres,
    const float* __restrict__ Wgate, const float* __restrict__ bgate,
    const float* __restrict__ wqe, const float* __restrict__ bqe,
    float* __restrict__ Q, float* __restrict__ K, float* __restrict__ V,
    float* __restrict__ SKIP, float* __restrict__ RES, float* __restrict__ WEQ,
    float* __restrict__ GATE, int n)
{
    int nodeBase = blockIdx.x * ROWS;
    int tid = threadIdx.x;

    for (int chunk = 0; chunk < 3; ++chunk) {
        int col = chunk * 256 + tid;
        const float* wptr;
        const float* bias;
        float* optr;
        int stride = 128, outw = 128, oc = 0;
        bool active = true, isgate = false;

        if (col < 512) {
            int sel = col >> 7;
            oc = col & 127;
            wptr = (sel == 0 ? Wq : sel == 1 ? Wk : sel == 2 ? Wv : Wskip) + oc;
            bias = (sel == 0 ? bq : sel == 1 ? bk : sel == 2 ? bv : bskip);
            optr = (sel == 0 ? Q : sel == 1 ? K : sel == 2 ? V : SKIP);
        } else if (col < 640) {
            oc = col - 512; wptr = Wres + oc; bias = bres; optr = RES;
        } else if (col < 704) {
            oc = col - 640; wptr = wqe + oc; bias = bqe; optr = WEQ;
            stride = 64; outw = 64;
        } else if (col == 704) {
            oc = 0; wptr = Wgate; bias = bgate; optr = GATE;
            stride = 1; outw = 1; isgate = true;
        } else {
            active = false; wptr = Wq; bias = bq; optr = nullptr;
        }

        float b = active ? bias[oc] : 0.f;
        float acc[ROWS];
#pragma unroll
        for (int r = 0; r < ROWS; ++r) acc[r] = b;

        for (int kh = 0; kh < 128; kh += 64) {
            float wreg[64];
#pragma unroll
            for (int kk = 0; kk < 64; ++kk)
                wreg[kk] = active ? wptr[(size_t)(kh + kk) * stride] : 0.f;
#pragma unroll
            for (int r = 0; r < ROWS; ++r) {
                int nd = nodeBase + r;
                if (nd > n - 1) nd = n - 1;  // clamp OOB tail rows (not stored)
                const float* xr = x + (size_t)nd * 128 + kh;
                float a = acc[r];
#pragma unroll
                for (int kk = 0; kk < 64; ++kk) a += xr[kk] * wreg[kk];
                acc[r] = a;
            }
        }

        if (active) {
#pragma unroll
            for (int r = 0; r < ROWS; ++r) {
                int node = nodeBase + r;
                if (node < n) {
                    float v = acc[r];
                    if (isgate) v = 1.f / (1.f + __expf(-v));
                    optr[(size_t)node * outw + oc] = v;
                }
            }
        }
    }
}

// ---------------------------------------------------------------------------
// CSR build: histogram -> 2-level exclusive scan -> scatter (int atomics only)
// ---------------------------------------------------------------------------
__global__ __launch_bounds__(256) void k_hist(const int* __restrict__ ei,
                                              int* __restrict__ deg, int E)
{
    int e = blockIdx.x * 256 + threadIdx.x;
    if (e < E) atomicAdd(&deg[ei[E + e]], 1);
}

__global__ __launch_bounds__(256) void k_scan1(const int* __restrict__ deg,
                                               int* __restrict__ rs,
                                               int* __restrict__ cs, int n)
{
    __shared__ int sh[256];
    int base = blockIdx.x * 1024;
    int t = threadIdx.x;
    int idx = base + t * 4;
    int v[4];
#pragma unroll
    for (int k = 0; k < 4; ++k) v[k] = (idx + k < n) ? deg[idx + k] : 0;
    int sum = v[0] + v[1] + v[2] + v[3];
    sh[t] = sum;
    __syncthreads();
    for (int off = 1; off < 256; off <<= 1) {
        int add = (t >= off) ? sh[t - off] : 0;
        __syncthreads();
        sh[t] += add;
        __syncthreads();
    }
    int run = sh[t] - sum;  // exclusive within chunk
    if (t == 255) cs[blockIdx.x] = sh[255];
#pragma unroll
    for (int k = 0; k < 4; ++k) {
        if (idx + k < n) rs[idx + k] = run;
        run += v[k];
    }
}

__global__ void k_scan2(int* __restrict__ cs, int nc)
{
    __shared__ int sh[64];
    int t = threadIdx.x;
    sh[t] = (t < nc) ? cs[t] : 0;
    __syncthreads();
    if (t == 0) {
        int acc = 0;
        for (int i = 0; i < nc; ++i) { int v = sh[i]; sh[i] = acc; acc += v; }
    }
    __syncthreads();
    if (t < nc) cs[t] = sh[t];
}

__global__ __launch_bounds__(256) void k_scan3(int* __restrict__ rs,
                                               const int* __restrict__ cs,
                                               int* __restrict__ cur, int n, int E)
{
    int i = blockIdx.x * 256 + threadIdx.x;
    if (i < n) {
        int v = rs[i] + cs[i >> 10];
        rs[i] = v;
        cur[i] = v;
    } else if (i == n) {
        rs[n] = E;
    }
}

__global__ __launch_bounds__(256) void k_scatter(const int* __restrict__ ei,
                                                 int* __restrict__ cur,
                                                 int* __restrict__ seid,
                                                 int* __restrict__ ssrc, int E)
{
    int e = blockIdx.x * 256 + threadIdx.x;
    if (e < E) {
        int d = ei[E + e];
        int pos = atomicAdd(&cur[d], 1);
        seid[pos] = e;
        ssrc[pos] = ei[e];
    }
}

// ---------------------------------------------------------------------------
// K3: node-centric attention pass. One wave (64 lanes) per node; lane owns
// channels {lane, lane+64} of the 128-dim and channel lane of the 64-dim.
// alpha = (Q[i].K[j] + ea.WeQ[i]) / sqrt(128); no max-subtraction (|alpha|<~0.3).
// Outputs: T[i] = sum ex*V[j], S[i] = sum ex*ea, denom[i] = sum ex.
// ---------------------------------------------------------------------------
__device__ inline float wave_allreduce(float v)
{
    v += __shfl_xor(v, 32);
    v += __shfl_xor(v, 16);
    v += __shfl_xor(v, 8);
    v += __shfl_xor(v, 4);
    v += __shfl_xor(v, 2);
    v += __shfl_xor(v, 1);
    return v;
}

__global__ __launch_bounds__(256) void k_attn(
    const float* __restrict__ Q, const float* __restrict__ K,
    const float* __restrict__ V, const float* __restrict__ WEQ,
    const float* __restrict__ ea,
    const int* __restrict__ rs, const int* __restrict__ seid,
    const int* __restrict__ ssrc,
    float* __restrict__ T, float* __restrict__ S, float* __restrict__ denom,
    int n)
{
    int node = blockIdx.x * 4 + (threadIdx.x >> 6);
    int lane = threadIdx.x & 63;
    if (node >= n) return;

    float q0 = Q[(size_t)node * 128 + lane];
    float q1 = Q[(size_t)node * 128 + 64 + lane];
    float wq = WEQ[(size_t)node * 64 + lane];

    float accd = 0.f, t0 = 0.f, t1 = 0.f, sA = 0.f;
    int beg = rs[node], end = rs[node + 1];

    for (int p = beg; p < end; ++p) {
        int j = ssrc[p];
        int eid = seid[p];
        const float* kr = K + (size_t)j * 128;
        const float* vr = V + (size_t)j * 128;
        const float* ar = ea + (size_t)eid * 64;
        float k0 = kr[lane], k1 = kr[64 + lane];
        float v0 = vr[lane], v1 = vr[64 + lane];
        float a = ar[lane];
        float part = q0 * k0 + q1 * k1 + wq * a;
        float alpha = wave_allreduce(part) * 0.08838834764831845f;  // 1/sqrt(128)
        float ex = __expf(alpha);
        accd += ex;
        t0 += ex * v0;
        t1 += ex * v1;
        sA += ex * a;
    }

    T[(size_t)node * 128 + lane] = t0;
    T[(size_t)node * 128 + 64 + lane] = t1;
    S[(size_t)node * 64 + lane] = sA;
    if (lane == 0) denom[node] = accd;
}

// ---------------------------------------------------------------------------
// K4: epilogue. attn = (T + S@We)/denom + skip; LayerNorm; ReLU; gated blend.
// One wave per node; We staged in LDS (32 KB).
// ---------------------------------------------------------------------------
__global__ __launch_bounds__(256) void k_final(
    const float* __restrict__ T, const float* __restrict__ S,
    const float* __restrict__ denom, const float* __restrict__ SKIP,
    const float* __restrict__ RES, const float* __restrict__ GATE,
    const float* __restrict__ We, const float* __restrict__ ln_g,
    const float* __restrict__ ln_b, float* __restrict__ out, int n)
{
    __shared__ float sWe[64 * 128];
    for (int i = threadIdx.x; i < 64 * 128; i += 256) sWe[i] = We[i];
    __syncthreads();

    int node = blockIdx.x * 4 + (threadIdx.x >> 6);
    int lane = threadIdx.x & 63;
    if (node >= n) return;

    float sv = S[(size_t)node * 64 + lane];
    float a0 = T[(size_t)node * 128 + lane];
    float a1 = T[(size_t)node * 128 + 64 + lane];
#pragma unroll 16
    for (int m = 0; m < 64; ++m) {
        float sm = __shfl(sv, m);
        a0 += sm * sWe[m * 128 + lane];
        a1 += sm * sWe[m * 128 + 64 + lane];
    }

    float d = denom[node];
    float rcp = d > 0.f ? 1.f / d : 0.f;  // zero-degree node -> attn = 0
    a0 = a0 * rcp + SKIP[(size_t)node * 128 + lane];
    a1 = a1 * rcp + SKIP[(size_t)node * 128 + 64 + lane];

    float s = wave_allreduce(a0 + a1);
    float mean = s * (1.f / 128.f);
    float d0 = a0 - mean, d1 = a1 - mean;
    float vs = wave_allreduce(d0 * d0 + d1 * d1);
    float inv = rsqrtf(vs * (1.f / 128.f) + 1e-5f);
    float n0 = d0 * inv * ln_g[lane] + ln_b[lane];
    float n1 = d1 * inv * ln_g[64 + lane] + ln_b[64 + lane];
    n0 = fmaxf(n0, 0.f);
    n1 = fmaxf(n1, 0.f);

    float g = GATE[node];
    float r0 = RES[(size_t)node * 128 + lane];
    float r1 = RES[(size_t)node * 128 + 64 + lane];
    out[(size_t)node * 128 + lane] = g * n0 + (1.f - g) * r0;
    out[(size_t)node * 128 + 64 + lane] = g * n1 + (1.f - g) * r1;
}

// ---------------------------------------------------------------------------
extern "C" void kernel_launch(void* const* d_in, const int* in_sizes, int n_in,
                              void* d_out, int out_size, void* d_ws, size_t ws_size,
                              hipStream_t stream)
{
    const float* x     = (const float*)d_in[0];
    const int*   ei    = (const int*)d_in[1];
    const float* ea    = (const float*)d_in[2];
    const float* Wq    = (const float*)d_in[3];
    const float* bq    = (const float*)d_in[4];
    const float* Wk    = (const float*)d_in[5];
    const float* bk    = (const float*)d_in[6];
    const float* Wv    = (const float*)d_in[7];
    const float* bv    = (const float*)d_in[8];
    const float* We    = (const float*)d_in[9];
    const float* Wskip = (const float*)d_in[10];
    const float* bskip = (const float*)d_in[11];
    const float* ln_g  = (const float*)d_in[12];
    const float* ln_b  = (const float*)d_in[13];
    const float* Wres  = (const float*)d_in[14];
    const float* bres  = (const float*)d_in[15];
    const float* Wgate = (const float*)d_in[16];
    const float* bgate = (const float*)d_in[17];
    float* out = (float*)d_out;

    float* W = (float*)d_ws;
    size_t o = 0;
    auto falloc = [&](size_t e) { size_t r = o; o += e; return r; };
    size_t oQ    = falloc((size_t)NN * 128);
    size_t oK    = falloc((size_t)NN * 128);
    size_t oV    = falloc((size_t)NN * 128);
    size_t oSKIP = falloc((size_t)NN * 128);
    size_t oRES  = falloc((size_t)NN * 128);
    size_t oT    = falloc((size_t)NN * 128);
    size_t oWEQ  = falloc((size_t)NN * 64);
    size_t oS    = falloc((size_t)NN * 64);
    size_t oGATE = falloc(NN);
    size_t oDEN  = falloc(NN);
    size_t oWQE  = falloc(8192);
    size_t oBQE  = falloc(64);

    int* IB = (int*)(W + o);
    size_t io = 0;
    auto ialloc = [&](size_t e) { size_t r = io; io += e; return r; };
    size_t oDEG  = ialloc(NN);
    size_t oRS   = ialloc(NN + 1);
    size_t oCUR  = ialloc(NN);
    size_t oCS   = ialloc(64);
    size_t oSEID = ialloc(EE);
    size_t oSSRC = ialloc(EE);

    hipMemsetAsync(IB + oDEG, 0, NN * sizeof(int), stream);

    k_wprep<<<33, 256, 0, stream>>>(Wq, bq, We, W + oWQE, W + oBQE);

    k_nodeproj<<<(NN + ROWS - 1) / ROWS, 256, 0, stream>>>(
        x, Wq, bq, Wk, bk, Wv, bv, Wskip, bskip, Wres, bres, Wgate, bgate,
        W + oWQE, W + oBQE,
        W + oQ, W + oK, W + oV, W + oSKIP, W + oRES, W + oWEQ, W + oGATE, NN);

    k_hist<<<(EE + 255) / 256, 256, 0, stream>>>(ei, IB + oDEG, EE);
    k_scan1<<<49, 256, 0, stream>>>(IB + oDEG, IB + oRS, IB + oCS, NN);
    k_scan2<<<1, 64, 0, stream>>>(IB + oCS, 49);
    k_scan3<<<(NN + 256) / 256, 256, 0, stream>>>(IB + oRS, IB + oCS, IB + oCUR, NN, EE);
    k_scatter<<<(EE + 255) / 256, 256, 0, stream>>>(ei, IB + oCUR, IB + oSEID, IB + oSSRC, EE);

    k_attn<<<NN / 4, 256, 0, stream>>>(W + oQ, W + oK, W + oV, W + oWEQ, ea,
                                       IB + oRS, IB + oSEID, IB + oSSRC,
                                       W + oT, W + oS, W + oDEN, NN);

    k_final<<<NN / 4, 256, 0, stream>>>(W + oT, W + oS, W + oDEN, W + oSKIP,
                                        W + oRES, W + oGATE, We, ln_g, ln_b,
                                        out, NN);
}

// Round 2
// 694.525 us; speedup vs baseline: 1.7142x; 1.7142x over previous
//
#include <hip/hip_runtime.h>
#include <math.h>

#define NN 50000
#define EE 800000
#define NPAD 50048           // 782 * 64
#define PC 768               // packed column count
// P column map: [0,128) Q | [128,256) K | [256,384) V | [384,512) SKIP |
//               [512,640) RES | [640,704) WEQ | 704 GATE | [705,768) pad

typedef short bf16x8 __attribute__((ext_vector_type(8)));
typedef float f32x4 __attribute__((ext_vector_type(4)));

__device__ inline short f2bf(float f)
{
    unsigned u = __float_as_uint(f);
    u = u + 0x7fff + ((u >> 16) & 1);   // RNE
    return (short)(u >> 16);
}

// ---------------------------------------------------------------------------
// K0: weight prep  wqe[r][m] = sum_c Wq[r][c] * We[m][c]   ([128,64])
//     bqe[m]       = sum_c bq[c] * We[m][c]
// ---------------------------------------------------------------------------
__global__ __launch_bounds__(256) void k_wprep(const float* __restrict__ Wq,
                                               const float* __restrict__ bq,
                                               const float* __restrict__ We,
                                               float* __restrict__ wqe,
                                               float* __restrict__ bqe)
{
    int idx = blockIdx.x * 256 + threadIdx.x;
    if (idx < 8192) {
        int r = idx >> 6, m = idx & 63;
        float acc = 0.f;
        for (int c = 0; c < 128; ++c) acc += Wq[r * 128 + c] * We[m * 128 + c];
        wqe[r * 64 + m] = acc;
    } else if (idx < 8256) {
        int m = idx - 8192;
        float acc = 0.f;
        for (int c = 0; c < 128; ++c) acc += bq[c] * We[m * 128 + c];
        bqe[m] = acc;
    }
}

// ---------------------------------------------------------------------------
// K1a: pack x -> bf16 [NPAD][128], zero pad rows
// ---------------------------------------------------------------------------
__global__ __launch_bounds__(256) void k_packx(const float* __restrict__ x,
                                               short* __restrict__ Xb)
{
    int t = blockIdx.x * 256 + threadIdx.x;   // one thread = 4 elements
    int base = t * 4;
    if (base >= NPAD * 128) return;
    short s0 = 0, s1 = 0, s2 = 0, s3 = 0;
    if (base < NN * 128) {
        const float4 v = *(const float4*)(x + base);
        s0 = f2bf(v.x); s1 = f2bf(v.y); s2 = f2bf(v.z); s3 = f2bf(v.w);
    }
    short4 o; o.x = s0; o.y = s1; o.z = s2; o.w = s3;
    *(short4*)(Xb + base) = o;
}

// ---------------------------------------------------------------------------
// K1b: pack transposed weight  WT[col][k] (bf16, [768][128]) + bias[768]
// ---------------------------------------------------------------------------
__global__ __launch_bounds__(256) void k_packw(
    const float* __restrict__ Wq, const float* __restrict__ bq,
    const float* __restrict__ Wk, const float* __restrict__ bk,
    const float* __restrict__ Wv, const float* __restrict__ bv,
    const float* __restrict__ Wskip, const float* __restrict__ bskip,
    const float* __restrict__ Wres, const float* __restrict__ bres,
    const float* __restrict__ Wgate, const float* __restrict__ bgate,
    const float* __restrict__ wqe, const float* __restrict__ bqe,
    short* __restrict__ WT, float* __restrict__ bias)
{
    int idx = blockIdx.x * 256 + threadIdx.x;
    if (idx < PC * 128) {
        int col = idx >> 7, k = idx & 127;
        float v;
        if (col < 128)      v = Wq[k * 128 + col];
        else if (col < 256) v = Wk[k * 128 + (col - 128)];
        else if (col < 384) v = Wv[k * 128 + (col - 256)];
        else if (col < 512) v = Wskip[k * 128 + (col - 384)];
        else if (col < 640) v = Wres[k * 128 + (col - 512)];
        else if (col < 704) v = wqe[k * 64 + (col - 640)];
        else if (col == 704) v = Wgate[k];
        else                v = 0.f;
        WT[col * 128 + k] = f2bf(v);
    } else if (idx < PC * 128 + PC) {
        int col = idx - PC * 128;
        float b;
        if (col < 128)      b = bq[col];
        else if (col < 256) b = bk[col - 128];
        else if (col < 384) b = bv[col - 256];
        else if (col < 512) b = bskip[col - 384];
        else if (col < 640) b = bres[col - 512];
        else if (col < 704) b = bqe[col - 640];
        else if (col == 704) b = bgate[0];
        else                b = 0.f;
        bias[col] = b;
    }
}

// ---------------------------------------------------------------------------
// K2: MFMA GEMM  P[row][col] = Xb[row][:] . WT[col][:] + bias[col]
// Block tile 64x64, 4 waves (16 rows x 64 cols each), K=128 fully in LDS.
// Row pad +8 shorts -> 2-way LDS bank aliasing only (free).
// ---------------------------------------------------------------------------
#define LROW 136
__global__ __launch_bounds__(256) void k_gemm(const short* __restrict__ Xb,
                                              const short* __restrict__ WT,
                                              const float* __restrict__ bias,
                                              float* __restrict__ P)
{
    __shared__ short Al[64 * LROW];
    __shared__ short Bl[64 * LROW];

    int bm = blockIdx.x;          // 782 row tiles
    int bn = blockIdx.y;          // 12 col tiles
    int tid = threadIdx.x;

    const short* gA = Xb + (size_t)bm * 64 * 128;
    const short* gB = WT + (size_t)bn * 64 * 128;

#pragma unroll
    for (int it = 0; it < 4; ++it) {
        int g = it * 256 + tid;           // unit = 8 shorts (16 B)
        int row = g >> 4, c8 = g & 15;
        bf16x8 va = *(const bf16x8*)(gA + g * 8);
        bf16x8 vb = *(const bf16x8*)(gB + g * 8);
        *(bf16x8*)&Al[row * LROW + c8 * 8] = va;
        *(bf16x8*)&Bl[row * LROW + c8 * 8] = vb;
    }
    __syncthreads();

    int wave = tid >> 6, lane = tid & 63;
    int quad = lane >> 4, l16 = lane & 15;
    int r0 = wave * 16;

    f32x4 acc[4] = {};
#pragma unroll
    for (int ks = 0; ks < 4; ++ks) {
        int k0 = ks * 32 + quad * 8;
        bf16x8 af = *(const bf16x8*)&Al[(r0 + l16) * LROW + k0];
#pragma unroll
        for (int cn = 0; cn < 4; ++cn) {
            bf16x8 bfr = *(const bf16x8*)&Bl[(cn * 16 + l16) * LROW + k0];
            acc[cn] = __builtin_amdgcn_mfma_f32_16x16x32_bf16(af, bfr, acc[cn], 0, 0, 0);
        }
    }

    int growb = bm * 64 + r0 + quad * 4;
#pragma unroll
    for (int cn = 0; cn < 4; ++cn) {
        int gcol = bn * 64 + cn * 16 + l16;
        float b = bias[gcol];
#pragma unroll
        for (int i = 0; i < 4; ++i) {
            int grow = growb + i;
            if (grow < NN) {
                float v = acc[cn][i] + b;
                if (gcol == 704) v = 1.f / (1.f + __expf(-v));
                P[(size_t)grow * PC + gcol] = v;
            }
        }
    }
}

// ---------------------------------------------------------------------------
// CSR build: histogram -> 2-level exclusive scan -> scatter (int atomics only)
// ---------------------------------------------------------------------------
__global__ __launch_bounds__(256) void k_hist(const int* __restrict__ ei,
                                              int* __restrict__ deg, int E)
{
    int e = blockIdx.x * 256 + threadIdx.x;
    if (e < E) atomicAdd(&deg[ei[E + e]], 1);
}

__global__ __launch_bounds__(256) void k_scan1(const int* __restrict__ deg,
                                               int* __restrict__ rs,
                                               int* __restrict__ cs, int n)
{
    __shared__ int sh[256];
    int base = blockIdx.x * 1024;
    int t = threadIdx.x;
    int idx = base + t * 4;
    int v[4];
#pragma unroll
    for (int k = 0; k < 4; ++k) v[k] = (idx + k < n) ? deg[idx + k] : 0;
    int sum = v[0] + v[1] + v[2] + v[3];
    sh[t] = sum;
    __syncthreads();
    for (int off = 1; off < 256; off <<= 1) {
        int add = (t >= off) ? sh[t - off] : 0;
        __syncthreads();
        sh[t] += add;
        __syncthreads();
    }
    int run = sh[t] - sum;
    if (t == 255) cs[blockIdx.x] = sh[255];
#pragma unroll
    for (int k = 0; k < 4; ++k) {
        if (idx + k < n) rs[idx + k] = run;
        run += v[k];
    }
}

__global__ void k_scan2(int* __restrict__ cs, int nc)
{
    __shared__ int sh[64];
    int t = threadIdx.x;
    sh[t] = (t < nc) ? cs[t] : 0;
    __syncthreads();
    if (t == 0) {
        int acc = 0;
        for (int i = 0; i < nc; ++i) { int v = sh[i]; sh[i] = acc; acc += v; }
    }
    __syncthreads();
    if (t < nc) cs[t] = sh[t];
}

__global__ __launch_bounds__(256) void k_scan3(int* __restrict__ rs,
                                               const int* __restrict__ cs,
                                               int* __restrict__ cur, int n, int E)
{
    int i = blockIdx.x * 256 + threadIdx.x;
    if (i < n) {
        int v = rs[i] + cs[i >> 10];
        rs[i] = v;
        cur[i] = v;
    } else if (i == n) {
        rs[n] = E;
    }
}

__global__ __launch_bounds__(256) void k_scatter(const int* __restrict__ ei,
                                                 int* __restrict__ cur,
                                                 int* __restrict__ seid,
                                                 int* __restrict__ ssrc, int E)
{
    int e = blockIdx.x * 256 + threadIdx.x;
    if (e < E) {
        int d = ei[E + e];
        int pos = atomicAdd(&cur[d], 1);
        seid[pos] = e;
        ssrc[pos] = ei[e];
    }
}

// ---------------------------------------------------------------------------
// K3: node-centric attention. One wave per node; lane owns channels
// {lane, lane+64} of 128-dim and channel lane of 64-dim.
// alpha = (Q[i].K[j] + ea.WeQ[i]) / sqrt(128); no max-subtraction.
// ---------------------------------------------------------------------------
__device__ inline float wave_allreduce(float v)
{
    v += __shfl_xor(v, 32);
    v += __shfl_xor(v, 16);
    v += __shfl_xor(v, 8);
    v += __shfl_xor(v, 4);
    v += __shfl_xor(v, 2);
    v += __shfl_xor(v, 1);
    return v;
}

__global__ __launch_bounds__(256) void k_attn(
    const float* __restrict__ P, const float* __restrict__ ea,
    const int* __restrict__ rs, const int* __restrict__ seid,
    const int* __restrict__ ssrc,
    float* __restrict__ T, float* __restrict__ S, float* __restrict__ denom,
    int n)
{
    int node = blockIdx.x * 4 + (threadIdx.x >> 6);
    int lane = threadIdx.x & 63;
    if (node >= n) return;

    const float* Prow = P + (size_t)node * PC;
    float q0 = Prow[lane];
    float q1 = Prow[64 + lane];
    float wq = Prow[640 + lane];

    float accd = 0.f, t0 = 0.f, t1 = 0.f, sA = 0.f;
    int beg = rs[node], end = rs[node + 1];

    for (int p = beg; p < end; ++p) {
        int j = ssrc[p];
        int eid = seid[p];
        const float* kv = P + (size_t)j * PC + 128;   // K row, V row contiguous after
        const float* ar = ea + (size_t)eid * 64;
        float k0 = kv[lane], k1 = kv[64 + lane];
        float v0 = kv[128 + lane], v1 = kv[192 + lane];
        float a = ar[lane];
        float part = q0 * k0 + q1 * k1 + wq * a;
        float alpha = wave_allreduce(part) * 0.08838834764831845f;  // 1/sqrt(128)
        float ex = __expf(alpha);
        accd += ex;
        t0 += ex * v0;
        t1 += ex * v1;
        sA += ex * a;
    }

    T[(size_t)node * 128 + lane] = t0;
    T[(size_t)node * 128 + 64 + lane] = t1;
    S[(size_t)node * 64 + lane] = sA;
    if (lane == 0) denom[node] = accd;
}

// ---------------------------------------------------------------------------
// K4: epilogue. attn = (T + S@We)/denom + skip; LayerNorm; ReLU; gated blend.
// ---------------------------------------------------------------------------
__global__ __launch_bounds__(256) void k_final(
    const float* __restrict__ T, const float* __restrict__ S,
    const float* __restrict__ denom, const float* __restrict__ P,
    const float* __restrict__ We, const float* __restrict__ ln_g,
    const float* __restrict__ ln_b, float* __restrict__ out, int n)
{
    __shared__ float sWe[64 * 128];
    for (int i = threadIdx.x; i < 64 * 128; i += 256) sWe[i] = We[i];
    __syncthreads();

    int node = blockIdx.x * 4 + (threadIdx.x >> 6);
    int lane = threadIdx.x & 63;
    if (node >= n) return;

    const float* Prow = P + (size_t)node * PC;

    float sv = S[(size_t)node * 64 + lane];
    float a0 = T[(size_t)node * 128 + lane];
    float a1 = T[(size_t)node * 128 + 64 + lane];
#pragma unroll 16
    for (int m = 0; m < 64; ++m) {
        float sm = __shfl(sv, m);
        a0 += sm * sWe[m * 128 + lane];
        a1 += sm * sWe[m * 128 + 64 + lane];
    }

    float d = denom[node];
    float rcp = d > 0.f ? 1.f / d : 0.f;
    a0 = a0 * rcp + Prow[384 + lane];
    a1 = a1 * rcp + Prow[448 + lane];

    float s = wave_allreduce(a0 + a1);
    float mean = s * (1.f / 128.f);
    float d0 = a0 - mean, d1 = a1 - mean;
    float vs = wave_allreduce(d0 * d0 + d1 * d1);
    float inv = rsqrtf(vs * (1.f / 128.f) + 1e-5f);
    float n0 = d0 * inv * ln_g[lane] + ln_b[lane];
    float n1 = d1 * inv * ln_g[64 + lane] + ln_b[64 + lane];
    n0 = fmaxf(n0, 0.f);
    n1 = fmaxf(n1, 0.f);

    float g = Prow[704];
    float r0 = Prow[512 + lane];
    float r1 = Prow[576 + lane];
    out[(size_t)node * 128 + lane] = g * n0 + (1.f - g) * r0;
    out[(size_t)node * 128 + 64 + lane] = g * n1 + (1.f - g) * r1;
}

// ---------------------------------------------------------------------------
extern "C" void kernel_launch(void* const* d_in, const int* in_sizes, int n_in,
                              void* d_out, int out_size, void* d_ws, size_t ws_size,
                              hipStream_t stream)
{
    const float* x     = (const float*)d_in[0];
    const int*   ei    = (const int*)d_in[1];
    const float* ea    = (const float*)d_in[2];
    const float* Wq    = (const float*)d_in[3];
    const float* bq    = (const float*)d_in[4];
    const float* Wk    = (const float*)d_in[5];
    const float* bk    = (const float*)d_in[6];
    const float* Wv    = (const float*)d_in[7];
    const float* bv    = (const float*)d_in[8];
    const float* We    = (const float*)d_in[9];
    const float* Wskip = (const float*)d_in[10];
    const float* bskip = (const float*)d_in[11];
    const float* ln_g  = (const float*)d_in[12];
    const float* ln_b  = (const float*)d_in[13];
    const float* Wres  = (const float*)d_in[14];
    const float* bres  = (const float*)d_in[15];
    const float* Wgate = (const float*)d_in[16];
    const float* bgate = (const float*)d_in[17];
    float* out = (float*)d_out;

    float* W = (float*)d_ws;
    size_t o = 0;
    auto falloc = [&](size_t e) { size_t r = o; o += e; return r; };
    size_t oP    = falloc((size_t)NN * PC);       // packed projections
    size_t oT    = falloc((size_t)NN * 128);
    size_t oS    = falloc((size_t)NN * 64);
    size_t oDEN  = falloc(NN);
    size_t oWQE  = falloc(8192);
    size_t oBQE  = falloc(64);
    size_t oBIAS = falloc(PC);

    short* SB = (short*)(W + o);
    size_t oXB = 0;                                // [NPAD*128] bf16
    size_t oWT = oXB + (size_t)NPAD * 128;         // [768*128]  bf16
    size_t sh_total = oWT + (size_t)PC * 128;

    int* IB = (int*)(SB + ((sh_total + 1) & ~(size_t)1));
    size_t io = 0;
    auto ialloc = [&](size_t e) { size_t r = io; io += e; return r; };
    size_t oDEG  = ialloc(NN);
    size_t oRS   = ialloc(NN + 1);
    size_t oCUR  = ialloc(NN);
    size_t oCS   = ialloc(64);
    size_t oSEID = ialloc(EE);
    size_t oSSRC = ialloc(EE);

    hipMemsetAsync(IB + oDEG, 0, NN * sizeof(int), stream);

    k_wprep<<<33, 256, 0, stream>>>(Wq, bq, We, W + oWQE, W + oBQE);
    k_packx<<<(NPAD * 128 / 4 + 255) / 256, 256, 0, stream>>>(x, SB + oXB);
    k_packw<<<(PC * 128 + PC + 255) / 256, 256, 0, stream>>>(
        Wq, bq, Wk, bk, Wv, bv, Wskip, bskip, Wres, bres, Wgate, bgate,
        W + oWQE, W + oBQE, SB + oWT, W + oBIAS);

    dim3 ggrid(NPAD / 64, PC / 64);
    k_gemm<<<ggrid, 256, 0, stream>>>(SB + oXB, SB + oWT, W + oBIAS, W + oP);

    k_hist<<<(EE + 255) / 256, 256, 0, stream>>>(ei, IB + oDEG, EE);
    k_scan1<<<49, 256, 0, stream>>>(IB + oDEG, IB + oRS, IB + oCS, NN);
    k_scan2<<<1, 64, 0, stream>>>(IB + oCS, 49);
    k_scan3<<<(NN + 256) / 256, 256, 0, stream>>>(IB + oRS, IB + oCS, IB + oCUR, NN, EE);
    k_scatter<<<(EE + 255) / 256, 256, 0, stream>>>(ei, IB + oCUR, IB + oSEID, IB + oSSRC, EE);

    k_attn<<<NN / 4, 256, 0, stream>>>(W + oP, ea, IB + oRS, IB + oSEID, IB + oSSRC,
                                       W + oT, W + oS, W + oDEN, NN);

    k_final<<<NN / 4, 256, 0, stream>>>(W + oT, W + oS, W + oDEN, W + oP,
                                        We, ln_g, ln_b, out, NN);
}

// Round 3
// 655.866 us; speedup vs baseline: 1.8152x; 1.0589x over previous
//
#include <hip/hip_runtime.h>
#include <math.h>

#define NN 50000
#define EE 800000
#define NPAD 50048           // 391 * 128
#define PC 768               // packed column count
// P column map: [0,128) Q | [128,256) K | [256,384) V | [384,512) SKIP |
//               [512,640) RES | [640,704) WEQ | 704 GATE | [705,768) pad

typedef short bf16x8 __attribute__((ext_vector_type(8)));
typedef float f32x4 __attribute__((ext_vector_type(4)));

#define ASCALE 0.08838834764831845f   // 1/sqrt(128)

__device__ inline short f2bf(float f)
{
    unsigned u = __float_as_uint(f);
    u = u + 0x7fff + ((u >> 16) & 1);   // RNE
    return (short)(u >> 16);
}

// ---------------------------------------------------------------------------
// K0: weight prep  wqe[r][m] = sum_c Wq[r][c] * We[m][c]   ([128,64])
// ---------------------------------------------------------------------------
__global__ __launch_bounds__(256) void k_wprep(const float* __restrict__ Wq,
                                               const float* __restrict__ bq,
                                               const float* __restrict__ We,
                                               float* __restrict__ wqe,
                                               float* __restrict__ bqe)
{
    int idx = blockIdx.x * 256 + threadIdx.x;
    if (idx < 8192) {
        int r = idx >> 6, m = idx & 63;
        float acc = 0.f;
        for (int c = 0; c < 128; ++c) acc += Wq[r * 128 + c] * We[m * 128 + c];
        wqe[r * 64 + m] = acc;
    } else if (idx < 8256) {
        int m = idx - 8192;
        float acc = 0.f;
        for (int c = 0; c < 128; ++c) acc += bq[c] * We[m * 128 + c];
        bqe[m] = acc;
    }
}

// ---------------------------------------------------------------------------
// K1a: pack x -> bf16 [NPAD][128], zero pad rows
// ---------------------------------------------------------------------------
__global__ __launch_bounds__(256) void k_packx(const float* __restrict__ x,
                                               short* __restrict__ Xb)
{
    int t = blockIdx.x * 256 + threadIdx.x;
    int base = t * 4;
    if (base >= NPAD * 128) return;
    short s0 = 0, s1 = 0, s2 = 0, s3 = 0;
    if (base < NN * 128) {
        const float4 v = *(const float4*)(x + base);
        s0 = f2bf(v.x); s1 = f2bf(v.y); s2 = f2bf(v.z); s3 = f2bf(v.w);
    }
    short4 o; o.x = s0; o.y = s1; o.z = s2; o.w = s3;
    *(short4*)(Xb + base) = o;
}

// ---------------------------------------------------------------------------
// K1b: pack transposed weight  WT[col][k] (bf16, [768][128]) + bias[768]
// ---------------------------------------------------------------------------
__global__ __launch_bounds__(256) void k_packw(
    const float* __restrict__ Wq, const float* __restrict__ bq,
    const float* __restrict__ Wk, const float* __restrict__ bk,
    const float* __restrict__ Wv, const float* __restrict__ bv,
    const float* __restrict__ Wskip, const float* __restrict__ bskip,
    const float* __restrict__ Wres, const float* __restrict__ bres,
    const float* __restrict__ Wgate, const float* __restrict__ bgate,
    const float* __restrict__ wqe, const float* __restrict__ bqe,
    short* __restrict__ WT, float* __restrict__ bias)
{
    int idx = blockIdx.x * 256 + threadIdx.x;
    if (idx < PC * 128) {
        int col = idx >> 7, k = idx & 127;
        float v;
        if (col < 128)      v = Wq[k * 128 + col];
        else if (col < 256) v = Wk[k * 128 + (col - 128)];
        else if (col < 384) v = Wv[k * 128 + (col - 256)];
        else if (col < 512) v = Wskip[k * 128 + (col - 384)];
        else if (col < 640) v = Wres[k * 128 + (col - 512)];
        else if (col < 704) v = wqe[k * 64 + (col - 640)];
        else if (col == 704) v = Wgate[k];
        else                v = 0.f;
        WT[col * 128 + k] = f2bf(v);
    } else if (idx < PC * 128 + PC) {
        int col = idx - PC * 128;
        float b;
        if (col < 128)      b = bq[col];
        else if (col < 256) b = bk[col - 128];
        else if (col < 384) b = bv[col - 256];
        else if (col < 512) b = bskip[col - 384];
        else if (col < 640) b = bres[col - 512];
        else if (col < 704) b = bqe[col - 640];
        else if (col == 704) b = bgate[0];
        else                b = 0.f;
        bias[col] = b;
    }
}

// ---------------------------------------------------------------------------
// K2: MFMA GEMM  P[row][col] = Xb[row][:] . WT[col][:] + bias[col]
// Block tile 128x64, 4 waves (32 rows x 64 cols each), K=128 in LDS.
// Row pad +8 shorts -> 2-way LDS bank aliasing only (free, m136).
// ---------------------------------------------------------------------------
#define LROW 136
__global__ __launch_bounds__(256) void k_gemm(const short* __restrict__ Xb,
                                              const short* __restrict__ WT,
                                              const float* __restrict__ bias,
                                              float* __restrict__ P)
{
    __shared__ short Al[128 * LROW];
    __shared__ short Bl[64 * LROW];

    int bm = blockIdx.x;          // 391 row tiles
    int bn = blockIdx.y;          // 12 col tiles
    int tid = threadIdx.x;

    const short* gA = Xb + (size_t)bm * 128 * 128;
    const short* gB = WT + (size_t)bn * 64 * 128;

#pragma unroll
    for (int it = 0; it < 8; ++it) {
        int g = it * 256 + tid;           // unit = 8 shorts (16 B)
        int row = g >> 4, c8 = g & 15;
        *(bf16x8*)&Al[row * LROW + c8 * 8] = *(const bf16x8*)(gA + g * 8);
    }
#pragma unroll
    for (int it = 0; it < 4; ++it) {
        int g = it * 256 + tid;
        int row = g >> 4, c8 = g & 15;
        *(bf16x8*)&Bl[row * LROW + c8 * 8] = *(const bf16x8*)(gB + g * 8);
    }
    __syncthreads();

    int wave = tid >> 6, lane = tid & 63;
    int quad = lane >> 4, l16 = lane & 15;
    int r0 = wave * 32;

    f32x4 acc[2][4] = {};
#pragma unroll
    for (int ks = 0; ks < 4; ++ks) {
        int k0 = ks * 32 + quad * 8;
        bf16x8 af0 = *(const bf16x8*)&Al[(r0 + l16) * LROW + k0];
        bf16x8 af1 = *(const bf16x8*)&Al[(r0 + 16 + l16) * LROW + k0];
#pragma unroll
        for (int cn = 0; cn < 4; ++cn) {
            bf16x8 bfr = *(const bf16x8*)&Bl[(cn * 16 + l16) * LROW + k0];
            acc[0][cn] = __builtin_amdgcn_mfma_f32_16x16x32_bf16(af0, bfr, acc[0][cn], 0, 0, 0);
            acc[1][cn] = __builtin_amdgcn_mfma_f32_16x16x32_bf16(af1, bfr, acc[1][cn], 0, 0, 0);
        }
    }

#pragma unroll
    for (int half = 0; half < 2; ++half) {
        int growb = bm * 128 + r0 + half * 16 + quad * 4;
#pragma unroll
        for (int cn = 0; cn < 4; ++cn) {
            int gcol = bn * 64 + cn * 16 + l16;
            float b = bias[gcol];
#pragma unroll
            for (int i = 0; i < 4; ++i) {
                int grow = growb + i;
                if (grow < NN) {
                    float v = acc[half][cn][i] + b;
                    if (gcol == 704) v = 1.f / (1.f + __expf(-v));
                    P[(size_t)grow * PC + gcol] = v;
                }
            }
        }
    }
}

// ---------------------------------------------------------------------------
// CSR build: histogram -> 2-level exclusive scan -> scatter (int atomics only)
// ---------------------------------------------------------------------------
__global__ __launch_bounds__(256) void k_hist(const int* __restrict__ ei,
                                              int* __restrict__ deg, int E)
{
    int e = blockIdx.x * 256 + threadIdx.x;
    if (e < E) atomicAdd(&deg[ei[E + e]], 1);
}

__global__ __launch_bounds__(256) void k_scan1(const int* __restrict__ deg,
                                               int* __restrict__ rs,
                                               int* __restrict__ cs, int n)
{
    __shared__ int sh[256];
    int base = blockIdx.x * 1024;
    int t = threadIdx.x;
    int idx = base + t * 4;
    int v[4];
#pragma unroll
    for (int k = 0; k < 4; ++k) v[k] = (idx + k < n) ? deg[idx + k] : 0;
    int sum = v[0] + v[1] + v[2] + v[3];
    sh[t] = sum;
    __syncthreads();
    for (int off = 1; off < 256; off <<= 1) {
        int add = (t >= off) ? sh[t - off] : 0;
        __syncthreads();
        sh[t] += add;
        __syncthreads();
    }
    int run = sh[t] - sum;
    if (t == 255) cs[blockIdx.x] = sh[255];
#pragma unroll
    for (int k = 0; k < 4; ++k) {
        if (idx + k < n) rs[idx + k] = run;
        run += v[k];
    }
}

__global__ void k_scan2(int* __restrict__ cs, int nc)
{
    __shared__ int sh[64];
    int t = threadIdx.x;
    sh[t] = (t < nc) ? cs[t] : 0;
    __syncthreads();
    if (t == 0) {
        int acc = 0;
        for (int i = 0; i < nc; ++i) { int v = sh[i]; sh[i] = acc; acc += v; }
    }
    __syncthreads();
    if (t < nc) cs[t] = sh[t];
}

__global__ __launch_bounds__(256) void k_scan3(int* __restrict__ rs,
                                               const int* __restrict__ cs,
                                               int* __restrict__ cur, int n, int E)
{
    int i = blockIdx.x * 256 + threadIdx.x;
    if (i < n) {
        int v = rs[i] + cs[i >> 10];
        rs[i] = v;
        cur[i] = v;
    } else if (i == n) {
        rs[n] = E;
    }
}

__global__ __launch_bounds__(256) void k_scatter(const int* __restrict__ ei,
                                                 int* __restrict__ cur,
                                                 int2* __restrict__ sj, int E)
{
    int e = blockIdx.x * 256 + threadIdx.x;
    if (e < E) {
        int d = ei[E + e];
        int pos = atomicAdd(&cur[d], 1);
        int2 v; v.x = ei[e]; v.y = e;
        sj[pos] = v;
    }
}

// ---------------------------------------------------------------------------
// K3: node-centric attention, 4x unrolled edge loop with interleaved
// shuffle-reduce chains (4 independent dependency chains per wave).
// ---------------------------------------------------------------------------
__device__ inline float wave_allreduce(float v)
{
    v += __shfl_xor(v, 32);
    v += __shfl_xor(v, 16);
    v += __shfl_xor(v, 8);
    v += __shfl_xor(v, 4);
    v += __shfl_xor(v, 2);
    v += __shfl_xor(v, 1);
    return v;
}

__global__ __launch_bounds__(256) void k_attn(
    const float* __restrict__ P, const float* __restrict__ ea,
    const int* __restrict__ rs, const int2* __restrict__ sj,
    float* __restrict__ T, float* __restrict__ S, float* __restrict__ denom,
    int n)
{
    int node = blockIdx.x * 4 + (threadIdx.x >> 6);
    int lane = threadIdx.x & 63;
    if (node >= n) return;

    const float* Prow = P + (size_t)node * PC;
    float q0 = Prow[lane];
    float q1 = Prow[64 + lane];
    float wq = Prow[640 + lane];

    float accd = 0.f, t0 = 0.f, t1 = 0.f, sA = 0.f;
    int beg = rs[node], end = rs[node + 1];

    int p = beg;
    for (; p + 4 <= end; p += 4) {
        int2 s0 = sj[p], s1 = sj[p + 1], s2 = sj[p + 2], s3 = sj[p + 3];
        const float* kv0 = P + (size_t)s0.x * PC + 128;
        const float* kv1 = P + (size_t)s1.x * PC + 128;
        const float* kv2 = P + (size_t)s2.x * PC + 128;
        const float* kv3 = P + (size_t)s3.x * PC + 128;
        const float* ar0 = ea + (size_t)s0.y * 64;
        const float* ar1 = ea + (size_t)s1.y * 64;
        const float* ar2 = ea + (size_t)s2.y * 64;
        const float* ar3 = ea + (size_t)s3.y * 64;

        float k00 = kv0[lane], k01 = kv0[64 + lane];
        float v00 = kv0[128 + lane], v01 = kv0[192 + lane];
        float k10 = kv1[lane], k11 = kv1[64 + lane];
        float v10 = kv1[128 + lane], v11 = kv1[192 + lane];
        float k20 = kv2[lane], k21 = kv2[64 + lane];
        float v20 = kv2[128 + lane], v21 = kv2[192 + lane];
        float k30 = kv3[lane], k31 = kv3[64 + lane];
        float v30 = kv3[128 + lane], v31 = kv3[192 + lane];
        float a0 = __builtin_nontemporal_load(ar0 + lane);
        float a1 = __builtin_nontemporal_load(ar1 + lane);
        float a2 = __builtin_nontemporal_load(ar2 + lane);
        float a3 = __builtin_nontemporal_load(ar3 + lane);

        float p0 = q0 * k00 + q1 * k01 + wq * a0;
        float p1 = q0 * k10 + q1 * k11 + wq * a1;
        float p2 = q0 * k20 + q1 * k21 + wq * a2;
        float p3 = q0 * k30 + q1 * k31 + wq * a3;

#pragma unroll
        for (int o = 32; o > 0; o >>= 1) {
            p0 += __shfl_xor(p0, o);
            p1 += __shfl_xor(p1, o);
            p2 += __shfl_xor(p2, o);
            p3 += __shfl_xor(p3, o);
        }

        float ex0 = __expf(p0 * ASCALE);
        float ex1 = __expf(p1 * ASCALE);
        float ex2 = __expf(p2 * ASCALE);
        float ex3 = __expf(p3 * ASCALE);

        accd += (ex0 + ex1) + (ex2 + ex3);
        t0 += ex0 * v00 + ex1 * v10 + ex2 * v20 + ex3 * v30;
        t1 += ex0 * v01 + ex1 * v11 + ex2 * v21 + ex3 * v31;
        sA += ex0 * a0 + ex1 * a1 + ex2 * a2 + ex3 * a3;
    }

    for (; p < end; ++p) {
        int2 s0 = sj[p];
        const float* kv = P + (size_t)s0.x * PC + 128;
        const float* ar = ea + (size_t)s0.y * 64;
        float k0 = kv[lane], k1 = kv[64 + lane];
        float v0 = kv[128 + lane], v1 = kv[192 + lane];
        float a = __builtin_nontemporal_load(ar + lane);
        float part = q0 * k0 + q1 * k1 + wq * a;
        float ex = __expf(wave_allreduce(part) * ASCALE);
        accd += ex;
        t0 += ex * v0;
        t1 += ex * v1;
        sA += ex * a;
    }

    T[(size_t)node * 128 + lane] = t0;
    T[(size_t)node * 128 + 64 + lane] = t1;
    S[(size_t)node * 64 + lane] = sA;
    if (lane == 0) denom[node] = accd;
}

// ---------------------------------------------------------------------------
// K4: epilogue. attn = (T + S@We)/denom + skip; LayerNorm; ReLU; gated blend.
// ---------------------------------------------------------------------------
__global__ __launch_bounds__(256) void k_final(
    const float* __restrict__ T, const float* __restrict__ S,
    const float* __restrict__ denom, const float* __restrict__ P,
    const float* __restrict__ We, const float* __restrict__ ln_g,
    const float* __restrict__ ln_b, float* __restrict__ out, int n)
{
    __shared__ float sWe[64 * 128];
    for (int i = threadIdx.x; i < 64 * 128; i += 256) sWe[i] = We[i];
    __syncthreads();

    int node = blockIdx.x * 4 + (threadIdx.x >> 6);
    int lane = threadIdx.x & 63;
    if (node >= n) return;

    const float* Prow = P + (size_t)node * PC;

    float sv = S[(size_t)node * 64 + lane];
    float a0 = T[(size_t)node * 128 + lane];
    float a1 = T[(size_t)node * 128 + 64 + lane];
#pragma unroll 16
    for (int m = 0; m < 64; ++m) {
        float sm = __shfl(sv, m);
        a0 += sm * sWe[m * 128 + lane];
        a1 += sm * sWe[m * 128 + 64 + lane];
    }

    float d = denom[node];
    float rcp = d > 0.f ? 1.f / d : 0.f;
    a0 = a0 * rcp + Prow[384 + lane];
    a1 = a1 * rcp + Prow[448 + lane];

    float s = wave_allreduce(a0 + a1);
    float mean = s * (1.f / 128.f);
    float d0 = a0 - mean, d1 = a1 - mean;
    float vs = wave_allreduce(d0 * d0 + d1 * d1);
    float inv = rsqrtf(vs * (1.f / 128.f) + 1e-5f);
    float n0 = d0 * inv * ln_g[lane] + ln_b[lane];
    float n1 = d1 * inv * ln_g[64 + lane] + ln_b[64 + lane];
    n0 = fmaxf(n0, 0.f);
    n1 = fmaxf(n1, 0.f);

    float g = Prow[704];
    float r0 = Prow[512 + lane];
    float r1 = Prow[576 + lane];
    out[(size_t)node * 128 + lane] = g * n0 + (1.f - g) * r0;
    out[(size_t)node * 128 + 64 + lane] = g * n1 + (1.f - g) * r1;
}

// ---------------------------------------------------------------------------
extern "C" void kernel_launch(void* const* d_in, const int* in_sizes, int n_in,
                              void* d_out, int out_size, void* d_ws, size_t ws_size,
                              hipStream_t stream)
{
    const float* x     = (const float*)d_in[0];
    const int*   ei    = (const int*)d_in[1];
    const float* ea    = (const float*)d_in[2];
    const float* Wq    = (const float*)d_in[3];
    const float* bq    = (const float*)d_in[4];
    const float* Wk    = (const float*)d_in[5];
    const float* bk    = (const float*)d_in[6];
    const float* Wv    = (const float*)d_in[7];
    const float* bv    = (const float*)d_in[8];
    const float* We    = (const float*)d_in[9];
    const float* Wskip = (const float*)d_in[10];
    const float* bskip = (const float*)d_in[11];
    const float* ln_g  = (const float*)d_in[12];
    const float* ln_b  = (const float*)d_in[13];
    const float* Wres  = (const float*)d_in[14];
    const float* bres  = (const float*)d_in[15];
    const float* Wgate = (const float*)d_in[16];
    const float* bgate = (const float*)d_in[17];
    float* out = (float*)d_out;

    float* W = (float*)d_ws;
    size_t o = 0;
    auto falloc = [&](size_t e) { size_t r = o; o += e; return r; };
    size_t oP    = falloc((size_t)NN * PC);
    size_t oT    = falloc((size_t)NN * 128);
    size_t oS    = falloc((size_t)NN * 64);
    size_t oDEN  = falloc(NN);
    size_t oWQE  = falloc(8192);
    size_t oBQE  = falloc(64);
    size_t oBIAS = falloc(PC);

    short* SB = (short*)(W + o);
    size_t oXB = 0;                                // [NPAD*128] bf16
    size_t oWT = oXB + (size_t)NPAD * 128;         // [768*128]  bf16
    size_t sh_total = oWT + (size_t)PC * 128;

    int* IB = (int*)(SB + ((sh_total + 1) & ~(size_t)1));
    size_t io = 0;
    auto ialloc = [&](size_t e) { size_t r = io; io += e; return r; };
    size_t oSJ   = ialloc((size_t)2 * EE);         // int2, 8B-aligned at IB+0
    size_t oDEG  = ialloc(NN);
    size_t oRS   = ialloc(NN + 1);
    size_t oCUR  = ialloc(NN);
    size_t oCS   = ialloc(64);

    hipMemsetAsync(IB + oDEG, 0, NN * sizeof(int), stream);

    k_wprep<<<33, 256, 0, stream>>>(Wq, bq, We, W + oWQE, W + oBQE);
    k_packx<<<(NPAD * 128 / 4 + 255) / 256, 256, 0, stream>>>(x, SB + oXB);
    k_packw<<<(PC * 128 + PC + 255) / 256, 256, 0, stream>>>(
        Wq, bq, Wk, bk, Wv, bv, Wskip, bskip, Wres, bres, Wgate, bgate,
        W + oWQE, W + oBQE, SB + oWT, W + oBIAS);

    dim3 ggrid(NPAD / 128, PC / 64);
    k_gemm<<<ggrid, 256, 0, stream>>>(SB + oXB, SB + oWT, W + oBIAS, W + oP);

    k_hist<<<(EE + 255) / 256, 256, 0, stream>>>(ei, IB + oDEG, EE);
    k_scan1<<<49, 256, 0, stream>>>(IB + oDEG, IB + oRS, IB + oCS, NN);
    k_scan2<<<1, 64, 0, stream>>>(IB + oCS, 49);
    k_scan3<<<(NN + 256) / 256, 256, 0, stream>>>(IB + oRS, IB + oCS, IB + oCUR, NN, EE);
    k_scatter<<<(EE + 255) / 256, 256, 0, stream>>>(ei, IB + oCUR, (int2*)(IB + oSJ), EE);

    k_attn<<<NN / 4, 256, 0, stream>>>(W + oP, ea, IB + oRS, (const int2*)(IB + oSJ),
                                       W + oT, W + oS, W + oDEN, NN);

    k_final<<<NN / 4, 256, 0, stream>>>(W + oT, W + oS, W + oDEN, W + oP,
                                        We, ln_g, ln_b, out, NN);
}

// Round 5
// 589.461 us; speedup vs baseline: 2.0197x; 1.1127x over previous
//
#include <hip/hip_runtime.h>
#include <math.h>

#define NN 50000
#define EE 800000
#define NPAD 50048           // 391 * 128
#define PC 768               // packed column count
// P column map: [0,128) Q | [128,384) unused (K/V live in KVb as bf16) |
//               [384,512) SKIP | [512,640) RES | [640,704) WEQ | 704 GATE
// KVb[node] = 128 dwords: dword c in [0,64)  = (bf16 K[c] lo, bf16 K[c+64] hi)
//             dword c in [64,128) = (bf16 V[c-64] lo, bf16 V[c] hi)

typedef short bf16x8 __attribute__((ext_vector_type(8)));
typedef float f32x4 __attribute__((ext_vector_type(4)));

#define ASCALE 0.08838834764831845f   // 1/sqrt(128)

__device__ inline unsigned short f2bf(float f)
{
    unsigned u = __float_as_uint(f);
    u = u + 0x7fff + ((u >> 16) & 1);   // RNE
    return (unsigned short)(u >> 16);
}

// ---------------------------------------------------------------------------
// K0: weight prep  wqe[r][m] = sum_c Wq[r][c] * We[m][c]   ([128,64])
// ---------------------------------------------------------------------------
__global__ __launch_bounds__(256) void k_wprep(const float* __restrict__ Wq,
                                               const float* __restrict__ bq,
                                               const float* __restrict__ We,
                                               float* __restrict__ wqe,
                                               float* __restrict__ bqe)
{
    int idx = blockIdx.x * 256 + threadIdx.x;
    if (idx < 8192) {
        int r = idx >> 6, m = idx & 63;
        float acc = 0.f;
        for (int c = 0; c < 128; ++c) acc += Wq[r * 128 + c] * We[m * 128 + c];
        wqe[r * 64 + m] = acc;
    } else if (idx < 8256) {
        int m = idx - 8192;
        float acc = 0.f;
        for (int c = 0; c < 128; ++c) acc += bq[c] * We[m * 128 + c];
        bqe[m] = acc;
    }
}

// ---------------------------------------------------------------------------
// K1a: pack x -> bf16 [NPAD][128], zero pad rows
// ---------------------------------------------------------------------------
__global__ __launch_bounds__(256) void k_packx(const float* __restrict__ x,
                                               short* __restrict__ Xb)
{
    int t = blockIdx.x * 256 + threadIdx.x;
    int base = t * 4;
    if (base >= NPAD * 128) return;
    short s0 = 0, s1 = 0, s2 = 0, s3 = 0;
    if (base < NN * 128) {
        const float4 v = *(const float4*)(x + base);
        s0 = f2bf(v.x); s1 = f2bf(v.y); s2 = f2bf(v.z); s3 = f2bf(v.w);
    }
    short4 o; o.x = s0; o.y = s1; o.z = s2; o.w = s3;
    *(short4*)(Xb + base) = o;
}

// ---------------------------------------------------------------------------
// K1b: pack transposed weight WT[col][k] (bf16 [768][128]) + bias[768]
//      + WeTb[c][kk] (bf16 [128][72], row-padded, zeros in pad)
// ---------------------------------------------------------------------------
__global__ __launch_bounds__(256) void k_packw(
    const float* __restrict__ Wq, const float* __restrict__ bq,
    const float* __restrict__ Wk, const float* __restrict__ bk,
    const float* __restrict__ Wv, const float* __restrict__ bv,
    const float* __restrict__ Wskip, const float* __restrict__ bskip,
    const float* __restrict__ Wres, const float* __restrict__ bres,
    const float* __restrict__ Wgate, const float* __restrict__ bgate,
    const float* __restrict__ wqe, const float* __restrict__ bqe,
    const float* __restrict__ We,
    short* __restrict__ WT, float* __restrict__ bias,
    unsigned short* __restrict__ WeTb)
{
    int idx = blockIdx.x * 256 + threadIdx.x;
    if (idx < PC * 128) {
        int col = idx >> 7, k = idx & 127;
        float v;
        if (col < 128)      v = Wq[k * 128 + col];
        else if (col < 256) v = Wk[k * 128 + (col - 128)];
        else if (col < 384) v = Wv[k * 128 + (col - 256)];
        else if (col < 512) v = Wskip[k * 128 + (col - 384)];
        else if (col < 640) v = Wres[k * 128 + (col - 512)];
        else if (col < 704) v = wqe[k * 64 + (col - 640)];
        else if (col == 704) v = Wgate[k];
        else                v = 0.f;
        WT[col * 128 + k] = (short)f2bf(v);
    } else if (idx < PC * 128 + PC) {
        int col = idx - PC * 128;
        float b;
        if (col < 128)      b = bq[col];
        else if (col < 256) b = bk[col - 128];
        else if (col < 384) b = bv[col - 256];
        else if (col < 512) b = bskip[col - 384];
        else if (col < 640) b = bres[col - 512];
        else if (col < 704) b = bqe[col - 640];
        else if (col == 704) b = bgate[0];
        else                b = 0.f;
        bias[col] = b;
    } else if (idx < PC * 128 + PC + 128 * 72) {
        int i2 = idx - (PC * 128 + PC);
        int c = i2 / 72, kk = i2 % 72;
        WeTb[i2] = (kk < 64) ? f2bf(We[kk * 128 + c]) : (unsigned short)0;
    }
}

// ---------------------------------------------------------------------------
// K2: MFMA GEMM. Block tile 128x64, grid (bn fastest) for A-tile L2 reuse.
// bn in {2,3,4,5} (K/V cols) writes bf16 into KVb instead of fp32 P.
// ---------------------------------------------------------------------------
#define LROW 136
__global__ __launch_bounds__(256) void k_gemm(const short* __restrict__ Xb,
                                              const short* __restrict__ WT,
                                              const float* __restrict__ bias,
                                              float* __restrict__ P,
                                              unsigned short* __restrict__ KVb16)
{
    __shared__ short Al[128 * LROW];
    __shared__ short Bl[64 * LROW];

    int bn = blockIdx.x;          // 12 col tiles (fastest -> A reuse in L2)
    int bm = blockIdx.y;          // 391 row tiles
    int tid = threadIdx.x;

    const short* gA = Xb + (size_t)bm * 128 * 128;
    const short* gB = WT + (size_t)bn * 64 * 128;

#pragma unroll
    for (int it = 0; it < 8; ++it) {
        int g = it * 256 + tid;           // unit = 8 shorts (16 B)
        int row = g >> 4, c8 = g & 15;
        *(bf16x8*)&Al[row * LROW + c8 * 8] = *(const bf16x8*)(gA + g * 8);
    }
#pragma unroll
    for (int it = 0; it < 4; ++it) {
        int g = it * 256 + tid;
        int row = g >> 4, c8 = g & 15;
        *(bf16x8*)&Bl[row * LROW + c8 * 8] = *(const bf16x8*)(gB + g * 8);
    }
    __syncthreads();

    int wave = tid >> 6, lane = tid & 63;
    int quad = lane >> 4, l16 = lane & 15;
    int r0 = wave * 32;

    f32x4 acc[2][4] = {};
#pragma unroll
    for (int ks = 0; ks < 4; ++ks) {
        int k0 = ks * 32 + quad * 8;
        bf16x8 af0 = *(const bf16x8*)&Al[(r0 + l16) * LROW + k0];
        bf16x8 af1 = *(const bf16x8*)&Al[(r0 + 16 + l16) * LROW + k0];
#pragma unroll
        for (int cn = 0; cn < 4; ++cn) {
            bf16x8 bfr = *(const bf16x8*)&Bl[(cn * 16 + l16) * LROW + k0];
            acc[0][cn] = __builtin_amdgcn_mfma_f32_16x16x32_bf16(af0, bfr, acc[0][cn], 0, 0, 0);
            acc[1][cn] = __builtin_amdgcn_mfma_f32_16x16x32_bf16(af1, bfr, acc[1][cn], 0, 0, 0);
        }
    }

    bool isKV = (bn >= 2 && bn <= 5);
#pragma unroll
    for (int half = 0; half < 2; ++half) {
        int growb = bm * 128 + r0 + half * 16 + quad * 4;
#pragma unroll
        for (int cn = 0; cn < 4; ++cn) {
            int gcol = bn * 64 + cn * 16 + l16;
            float b = bias[gcol];
#pragma unroll
            for (int i = 0; i < 4; ++i) {
                int grow = growb + i;
                if (grow < NN) {
                    float v = acc[half][cn][i] + b;
                    if (isKV) {
                        int slot;
                        if (gcol < 192)      slot = (gcol - 128) * 2;
                        else if (gcol < 256) slot = (gcol - 192) * 2 + 1;
                        else if (gcol < 320) slot = 128 + (gcol - 256) * 2;
                        else                 slot = 128 + (gcol - 320) * 2 + 1;
                        KVb16[(size_t)grow * 256 + slot] = f2bf(v);
                    } else {
                        if (gcol == 704) v = 1.f / (1.f + __expf(-v));
                        P[(size_t)grow * PC + gcol] = v;
                    }
                }
            }
        }
    }
}

// ---------------------------------------------------------------------------
// CSR build
// ---------------------------------------------------------------------------
__global__ __launch_bounds__(256) void k_hist(const int* __restrict__ ei,
                                              int* __restrict__ deg, int E)
{
    int e = blockIdx.x * 256 + threadIdx.x;
    if (e < E) atomicAdd(&deg[ei[E + e]], 1);
}

__global__ __launch_bounds__(256) void k_scan1(const int* __restrict__ deg,
                                               int* __restrict__ rs,
                                               int* __restrict__ cs, int n)
{
    __shared__ int sh[256];
    int base = blockIdx.x * 1024;
    int t = threadIdx.x;
    int idx = base + t * 4;
    int v[4];
#pragma unroll
    for (int k = 0; k < 4; ++k) v[k] = (idx + k < n) ? deg[idx + k] : 0;
    int sum = v[0] + v[1] + v[2] + v[3];
    sh[t] = sum;
    __syncthreads();
    for (int off = 1; off < 256; off <<= 1) {
        int add = (t >= off) ? sh[t - off] : 0;
        __syncthreads();
        sh[t] += add;
        __syncthreads();
    }
    int run = sh[t] - sum;
    if (t == 255) cs[blockIdx.x] = sh[255];
#pragma unroll
    for (int k = 0; k < 4; ++k) {
        if (idx + k < n) rs[idx + k] = run;
        run += v[k];
    }
}

__global__ void k_scan2(int* __restrict__ cs, int nc)
{
    __shared__ int sh[64];
    int t = threadIdx.x;
    sh[t] = (t < nc) ? cs[t] : 0;
    __syncthreads();
    if (t == 0) {
        int acc = 0;
        for (int i = 0; i < nc; ++i) { int v = sh[i]; sh[i] = acc; acc += v; }
    }
    __syncthreads();
    if (t < nc) cs[t] = sh[t];
}

__global__ __launch_bounds__(256) void k_scan3(int* __restrict__ rs,
                                               const int* __restrict__ cs,
                                               int* __restrict__ cur, int n, int E)
{
    int i = blockIdx.x * 256 + threadIdx.x;
    if (i < n) {
        int v = rs[i] + cs[i >> 10];
        rs[i] = v;
        cur[i] = v;
    } else if (i == n) {
        rs[n] = E;
    }
}

__global__ __launch_bounds__(256) void k_scatter(const int* __restrict__ ei,
                                                 int* __restrict__ cur,
                                                 int2* __restrict__ sj, int E)
{
    int e = blockIdx.x * 256 + threadIdx.x;
    if (e < E) {
        int d = ei[E + e];
        int pos = atomicAdd(&cur[d], 1);
        int2 v; v.x = ei[e]; v.y = e;
        sj[pos] = v;
    }
}

// ---------------------------------------------------------------------------
// K3: fused attention + epilogue. One wave per node, 4 nodes/block.
// Gather: 8x unrolled, bf16 KV (2 dwords/edge) + fp32 ea (nontemporal).
// NOTE: ex is computed from an all-reduced alpha, so accd (sum of ex) is
// already lane-uniform — do NOT butterfly-reduce it again (round-4 bug:
// that scaled the denominator by 64x).
// Epilogue: S@We via MFMAs (A rows = 4 nodes; D rows 4-15 discarded),
// then (T + S@We)/denom + skip -> LayerNorm -> ReLU -> gated blend -> out.
// ---------------------------------------------------------------------------
__global__ __launch_bounds__(256) void k_attn_fused(
    const float* __restrict__ P, const unsigned int* __restrict__ KVb,
    const float* __restrict__ ea, const unsigned short* __restrict__ WeTb,
    const int* __restrict__ rs, const int2* __restrict__ sj,
    const float* __restrict__ ln_g, const float* __restrict__ ln_b,
    float* __restrict__ out)
{
    __shared__ unsigned short WeT_l[128 * 72];   // [col][k], row 144 B (16B mult)
    __shared__ unsigned short Sb_l[4 * 64];      // [node][k] bf16
    __shared__ float att_l[4 * 128];             // S@We result

    int tid = threadIdx.x;
    {   // stage WeT (4608 dwords)
        const unsigned int* src = (const unsigned int*)WeTb;
        unsigned int* dst = (unsigned int*)WeT_l;
        for (int i = tid; i < 128 * 36; i += 256) dst[i] = src[i];
    }

    int wave = tid >> 6, lane = tid & 63;
    int node = blockIdx.x * 4 + wave;            // grid is exactly NN/4

    const float* Prow = P + (size_t)node * PC;
    float q0 = Prow[lane];
    float q1 = Prow[64 + lane];
    float wq = Prow[640 + lane];

    float accd = 0.f, t0 = 0.f, t1 = 0.f, sA = 0.f;
    int beg = rs[node], end = rs[node + 1];

    int p = beg;
    for (; p + 8 <= end; p += 8) {
        float pp[8], aa[8], v0[8], v1[8];
#pragma unroll
        for (int u = 0; u < 8; ++u) {
            int2 s = sj[p + u];
            const unsigned int* kv = KVb + (size_t)s.x * 128;
            unsigned int kw = kv[lane];
            unsigned int vw = kv[64 + lane];
            float a = __builtin_nontemporal_load(ea + (size_t)s.y * 64 + lane);
            float k0 = __uint_as_float(kw << 16);
            float k1 = __uint_as_float(kw & 0xffff0000u);
            v0[u] = __uint_as_float(vw << 16);
            v1[u] = __uint_as_float(vw & 0xffff0000u);
            aa[u] = a;
            pp[u] = q0 * k0 + q1 * k1 + wq * a;
        }
#pragma unroll
        for (int o = 32; o > 0; o >>= 1) {
#pragma unroll
            for (int u = 0; u < 8; ++u) pp[u] += __shfl_xor(pp[u], o);
        }
#pragma unroll
        for (int u = 0; u < 8; ++u) {
            float ex = __expf(pp[u] * ASCALE);
            accd += ex;
            t0 += ex * v0[u];
            t1 += ex * v1[u];
            sA += ex * aa[u];
        }
    }
    for (; p < end; ++p) {
        int2 s = sj[p];
        const unsigned int* kv = KVb + (size_t)s.x * 128;
        unsigned int kw = kv[lane];
        unsigned int vw = kv[64 + lane];
        float a = __builtin_nontemporal_load(ea + (size_t)s.y * 64 + lane);
        float k0 = __uint_as_float(kw << 16);
        float k1 = __uint_as_float(kw & 0xffff0000u);
        float vv0 = __uint_as_float(vw << 16);
        float vv1 = __uint_as_float(vw & 0xffff0000u);
        float part = q0 * k0 + q1 * k1 + wq * a;
#pragma unroll
        for (int o = 32; o > 0; o >>= 1) part += __shfl_xor(part, o);
        float ex = __expf(part * ASCALE);
        accd += ex;
        t0 += ex * vv0;
        t1 += ex * vv1;
        sA += ex * a;
    }

    // accd is already lane-uniform (ex came from all-reduced alpha).

    // stage S (bf16) for MFMA
    Sb_l[wave * 64 + lane] = f2bf(sA);
    __syncthreads();   // orders WeT staging + Sb writes before MFMA reads

    // S@We: each wave computes 2 col-tiles of 16 for all 4 nodes
    {
        int quad = lane >> 4, l16 = lane & 15;
        int arow = l16 & 3;     // A rows 4-15 duplicate rows 0-3; D rows 4-15 unused
        bf16x8 a0 = *(const bf16x8*)&Sb_l[arow * 64 + quad * 8];
        bf16x8 a1 = *(const bf16x8*)&Sb_l[arow * 64 + 32 + quad * 8];
#pragma unroll
        for (int c2 = 0; c2 < 2; ++c2) {
            int cn = wave * 2 + c2;
            int r = cn * 16 + l16;
            bf16x8 b0 = *(const bf16x8*)&WeT_l[r * 72 + quad * 8];
            bf16x8 b1 = *(const bf16x8*)&WeT_l[r * 72 + 32 + quad * 8];
            f32x4 acc = {};
            acc = __builtin_amdgcn_mfma_f32_16x16x32_bf16(a0, b0, acc, 0, 0, 0);
            acc = __builtin_amdgcn_mfma_f32_16x16x32_bf16(a1, b1, acc, 0, 0, 0);
            if (quad == 0) {
#pragma unroll
                for (int i = 0; i < 4; ++i)
                    att_l[i * 128 + cn * 16 + l16] = acc[i];
            }
        }
    }
    __syncthreads();

    float rcp = accd > 0.f ? 1.f / accd : 0.f;
    float a0f = (t0 + att_l[wave * 128 + lane]) * rcp + Prow[384 + lane];
    float a1f = (t1 + att_l[wave * 128 + 64 + lane]) * rcp + Prow[448 + lane];

    float s = a0f + a1f;
#pragma unroll
    for (int o = 32; o > 0; o >>= 1) s += __shfl_xor(s, o);
    float mean = s * (1.f / 128.f);
    float d0 = a0f - mean, d1 = a1f - mean;
    float vs = d0 * d0 + d1 * d1;
#pragma unroll
    for (int o = 32; o > 0; o >>= 1) vs += __shfl_xor(vs, o);
    float inv = rsqrtf(vs * (1.f / 128.f) + 1e-5f);
    float n0 = d0 * inv * ln_g[lane] + ln_b[lane];
    float n1 = d1 * inv * ln_g[64 + lane] + ln_b[64 + lane];
    n0 = fmaxf(n0, 0.f);
    n1 = fmaxf(n1, 0.f);

    float g = Prow[704];
    float r0 = Prow[512 + lane];
    float r1 = Prow[576 + lane];
    out[(size_t)node * 128 + lane] = g * n0 + (1.f - g) * r0;
    out[(size_t)node * 128 + 64 + lane] = g * n1 + (1.f - g) * r1;
}

// ---------------------------------------------------------------------------
extern "C" void kernel_launch(void* const* d_in, const int* in_sizes, int n_in,
                              void* d_out, int out_size, void* d_ws, size_t ws_size,
                              hipStream_t stream)
{
    const float* x     = (const float*)d_in[0];
    const int*   ei    = (const int*)d_in[1];
    const float* ea    = (const float*)d_in[2];
    const float* Wq    = (const float*)d_in[3];
    const float* bq    = (const float*)d_in[4];
    const float* Wk    = (const float*)d_in[5];
    const float* bk    = (const float*)d_in[6];
    const float* Wv    = (const float*)d_in[7];
    const float* bv    = (const float*)d_in[8];
    const float* We    = (const float*)d_in[9];
    const float* Wskip = (const float*)d_in[10];
    const float* bskip = (const float*)d_in[11];
    const float* ln_g  = (const float*)d_in[12];
    const float* ln_b  = (const float*)d_in[13];
    const float* Wres  = (const float*)d_in[14];
    const float* bres  = (const float*)d_in[15];
    const float* Wgate = (const float*)d_in[16];
    const float* bgate = (const float*)d_in[17];
    float* out = (float*)d_out;

    float* W = (float*)d_ws;
    size_t o = 0;
    auto falloc = [&](size_t e) { size_t r = o; o += e; return r; };
    size_t oP    = falloc((size_t)NN * PC);
    size_t oWQE  = falloc(8192);
    size_t oBQE  = falloc(64);
    size_t oBIAS = falloc(PC);
    size_t oKVB  = falloc((size_t)NN * 128);      // uint-sized (bf16 KV pairs)

    short* SB = (short*)(W + o);
    size_t oXB  = 0;                               // [NPAD*128] bf16
    size_t oWT  = oXB + (size_t)NPAD * 128;        // [768*128]  bf16
    size_t oWET = oWT + (size_t)PC * 128;          // [128*72]   bf16
    size_t sh_total = oWET + 128 * 72;

    int* IB = (int*)(SB + ((sh_total + 1) & ~(size_t)1));
    size_t io = 0;
    auto ialloc = [&](size_t e) { size_t r = io; io += e; return r; };
    size_t oSJ   = ialloc((size_t)2 * EE);         // int2, 8B-aligned at IB+0
    size_t oDEG  = ialloc(NN);
    size_t oRS   = ialloc(NN + 1);
    size_t oCUR  = ialloc(NN);
    size_t oCS   = ialloc(64);

    hipMemsetAsync(IB + oDEG, 0, NN * sizeof(int), stream);

    k_wprep<<<33, 256, 0, stream>>>(Wq, bq, We, W + oWQE, W + oBQE);
    k_packx<<<(NPAD * 128 / 4 + 255) / 256, 256, 0, stream>>>(x, SB + oXB);
    k_packw<<<(PC * 128 + PC + 128 * 72 + 255) / 256, 256, 0, stream>>>(
        Wq, bq, Wk, bk, Wv, bv, Wskip, bskip, Wres, bres, Wgate, bgate,
        W + oWQE, W + oBQE, We, SB + oWT, W + oBIAS,
        (unsigned short*)(SB + oWET));

    dim3 ggrid(PC / 64, NPAD / 128);   // bn fastest -> A-tile L2 reuse
    k_gemm<<<ggrid, 256, 0, stream>>>(SB + oXB, SB + oWT, W + oBIAS, W + oP,
                                      (unsigned short*)(W + oKVB));

    k_hist<<<(EE + 255) / 256, 256, 0, stream>>>(ei, IB + oDEG, EE);
    k_scan1<<<49, 256, 0, stream>>>(IB + oDEG, IB + oRS, IB + oCS, NN);
    k_scan2<<<1, 64, 0, stream>>>(IB + oCS, 49);
    k_scan3<<<(NN + 256) / 256, 256, 0, stream>>>(IB + oRS, IB + oCS, IB + oCUR, NN, EE);
    k_scatter<<<(EE + 255) / 256, 256, 0, stream>>>(ei, IB + oCUR, (int2*)(IB + oSJ), EE);

    k_attn_fused<<<NN / 4, 256, 0, stream>>>(
        W + oP, (const unsigned int*)(W + oKVB), ea,
        (const unsigned short*)(SB + oWET),
        IB + oRS, (const int2*)(IB + oSJ), ln_g, ln_b, out);
}